// Round 16
// baseline (65.348 us; speedup 1.0000x reference)
//
#include <hip/hip_runtime.h>
#include <hip/hip_bf16.h>
#include <math.h>

// Problem constants
constexpr int Nimg = 4;
constexpr int Cin  = 256;
constexpr int Hc   = 64;
constexpr int Wc   = 64;
constexpr int HWc  = Hc * Wc;          // 4096
constexpr int Mrows = Nimg * HWc;      // 16384
constexpr int Gg   = 16;
constexpr int K2c  = 9;
constexpr int OMC  = Gg * K2c * 3;     // 432
constexpr int C2c  = 256;
constexpr float EPSc = 1e-5f;

typedef __attribute__((ext_vector_type(8))) short short8v;   // 8 bf16 bits
typedef __attribute__((ext_vector_type(4))) float f32x4;

__device__ __forceinline__ unsigned short f2bf(float f) {
    return __builtin_bit_cast(unsigned short, __float2bfloat16(f));
}
__device__ __forceinline__ float bf2f(unsigned short u) {
    return __builtin_bit_cast(float, (unsigned)u << 16);
}

__device__ __forceinline__ void gload16(const unsigned short* g, unsigned short* l) {
    __builtin_amdgcn_global_load_lds(
        (const __attribute__((address_space(1))) void*)g,
        (__attribute__((address_space(3))) void*)l, 16, 0, 0);
}

// Accumulate 8 bf16 channels (16B at p) with weight wk into acc[8].
__device__ __forceinline__ void acc8(const unsigned short* p, float wk, float* a) {
    const uint4 u = *reinterpret_cast<const uint4*>(p);
    a[0] += wk * __builtin_bit_cast(float, u.x << 16);
    a[1] += wk * __builtin_bit_cast(float, u.x & 0xffff0000u);
    a[2] += wk * __builtin_bit_cast(float, u.y << 16);
    a[3] += wk * __builtin_bit_cast(float, u.y & 0xffff0000u);
    a[4] += wk * __builtin_bit_cast(float, u.z << 16);
    a[5] += wk * __builtin_bit_cast(float, u.z & 0xffff0000u);
    a[6] += wk * __builtin_bit_cast(float, u.w << 16);
    a[7] += wk * __builtin_bit_cast(float, u.w & 0xffff0000u);
}

// ---------------------------------------------------------------------------
// Fused prep: blocks [0,1024) transpose+convert x (float4 reads);
// blocks [1024,2051) convert weights to transposed bf16 + concat bias.
// ---------------------------------------------------------------------------
__global__ __launch_bounds__(256) void prep(
    const float* __restrict__ x,
    const float* __restrict__ Wv, const float* __restrict__ Wom,
    const float* __restrict__ Wout,
    const float* __restrict__ bv, const float* __restrict__ bom,
    unsigned short* __restrict__ A,
    unsigned short* __restrict__ WallT, unsigned short* __restrict__ WoutT,
    float* __restrict__ ball)
{
    __shared__ float tile[64][65];
    const int t   = threadIdx.x;
    const int bid = blockIdx.x;
    if (bid < 1024) {
        const int p0 = (bid & 63) * 64;
        const int c0 = ((bid >> 6) & 3) * 64;
        const int n  = bid >> 8;
        const float* xb = x + ((size_t)n * Cin + c0) * HWc + p0;
        {
            const int cl = t >> 4;
            const int p4 = (t & 15) * 4;
#pragma unroll
            for (int i = 0; i < 4; i++) {
                const int c = i * 16 + cl;
                const float4 f = *reinterpret_cast<const float4*>(
                    xb + (size_t)c * HWc + p4);
                tile[c][p4 + 0] = f.x;
                tile[c][p4 + 1] = f.y;
                tile[c][p4 + 2] = f.z;
                tile[c][p4 + 3] = f.w;
            }
        }
        __syncthreads();
        unsigned short* Ab = A + ((size_t)(n * HWc) + p0) * Cin + c0;
#pragma unroll
        for (int i = 0; i < 8; i++) {
            const int p  = i * 8 + (t >> 5);
            const int c2 = (t & 31) * 2;
            const unsigned lo = f2bf(tile[c2][p]);
            const unsigned hi = f2bf(tile[c2 + 1][p]);
            *(unsigned*)(Ab + (size_t)p * Cin + c2) = lo | (hi << 16);
        }
        return;
    }
    const int e = (bid - 1024) * 256 + t;
    if (e < 65536) {                       // Wv -> WallT rows 0..255
        const int nc = e >> 8, k = e & 255;
        WallT[e] = f2bf(Wv[(size_t)k * 256 + nc]);
    } else if (e < 196608) {               // Wom -> WallT rows 256..767 (pad)
        const int e2 = e - 65536;
        const int nc = e2 >> 8, k = e2 & 255;
        WallT[e] = f2bf(nc < 432 ? Wom[(size_t)k * 432 + nc] : 0.f);
    } else if (e < 262144) {               // Wout -> WoutT
        const int e3 = e - 196608;
        const int nc = e3 >> 8, k = e3 & 255;
        WoutT[e3] = f2bf(Wout[(size_t)k * 256 + nc]);
    } else if (e < 262912) {               // concat bias
        const int i = e - 262144;
        ball[i] = (i < 256) ? bv[i] : ((i < 688) ? bom[i - 256] : 0.f);
    }
}

// ---------------------------------------------------------------------------
// Fused v+om GEMM: 64x128 tiles, 128 threads (2 waves, 64x64 each).
// Grid (6,256) = 1536 blocks = 6 blocks/CU: staging of one block overlaps
// MFMA of co-resident blocks. XCD-swizzled (32 row-blocks x 6 col per XCD,
// A slice 1MB L2-resident).
// ---------------------------------------------------------------------------
__global__ __launch_bounds__(128) void gemm_vom(
    const unsigned short* __restrict__ A,
    const unsigned short* __restrict__ Bt,
    const float* __restrict__ ball,
    unsigned short* __restrict__ vbf,
    unsigned short* __restrict__ ombf)
{
    __shared__ unsigned short As[64 * 32];     // 4KB
    __shared__ unsigned short Bs[128 * 32];    // 8KB
    const int t    = threadIdx.x;
    const int lane = t & 63;
    const int wc   = t >> 6;                   // wave col 0..1
    const int wub  = t & ~63;
    const int vid = blockIdx.x + 6 * blockIdx.y;   // 0..1535
    const int xcd = vid & 7;
    const int j8  = vid >> 3;                      // 0..191
    const int row0 = (xcd * 32 + j8 / 6) * 64;
    const int col0 = (j8 % 6) * 128;

    f32x4 acc[4][4];
#pragma unroll
    for (int m = 0; m < 4; m++)
#pragma unroll
        for (int n = 0; n < 4; n++) acc[m][n] = (f32x4)0.f;

    // staging granules: g = jj*128+t -> row g>>2, k-offset (g&3)*8
    const unsigned short* gA = A  + (size_t)(row0 + (t >> 2)) * 256 + (t & 3) * 8;
    const unsigned short* gB = Bt + (size_t)(col0 + (t >> 2)) * 256 + (t & 3) * 8;

    const int aoff = (lane & 15) * 32 + (lane >> 4) * 8;
    const int boff = ((wc * 64) + (lane & 15)) * 32 + (lane >> 4) * 8;

    for (int k0 = 0; k0 < 256; k0 += 32) {
#pragma unroll
        for (int jj = 0; jj < 2; jj++)         // A: 64 rows
            gload16(gA + (size_t)jj * 32 * 256 + k0, As + (jj * 128 + wub) * 8);
#pragma unroll
        for (int jj = 0; jj < 4; jj++)         // B: 128 cols
            gload16(gB + (size_t)jj * 32 * 256 + k0, Bs + (jj * 128 + wub) * 8);
        __syncthreads();

        short8v a_[4], b_[4];
#pragma unroll
        for (int m = 0; m < 4; m++)
            a_[m] = *(const short8v*)(As + aoff + m * 16 * 32);
#pragma unroll
        for (int n = 0; n < 4; n++)
            b_[n] = *(const short8v*)(Bs + boff + n * 16 * 32);
#pragma unroll
        for (int m = 0; m < 4; m++)
#pragma unroll
            for (int n = 0; n < 4; n++)
                acc[m][n] = __builtin_amdgcn_mfma_f32_16x16x32_bf16(
                    a_[m], b_[n], acc[m][n], 0, 0, 0);
        __syncthreads();
    }

    const int rb = row0 + ((lane >> 4) << 2);
#pragma unroll
    for (int n = 0; n < 4; n++) {
        const int gcol = col0 + wc * 64 + n * 16 + (lane & 15);
        const float bb = ball[gcol];
#pragma unroll
        for (int m = 0; m < 4; m++) {
#pragma unroll
            for (int r = 0; r < 4; r++) {
                const float val = acc[m][n][r] + bb;
                const int row = rb + m * 16 + r;
                if (gcol < 256) {
                    vbf[(size_t)row * 256 + gcol] = f2bf(val);
                } else {
                    const int oc = gcol - 256;
                    if (oc < 432)
                        ombf[(size_t)row * 432 + oc] = f2bf(val);
                }
            }
        }
    }
}

// ---------------------------------------------------------------------------
// Deformable sampling, LDS-tiled + channel-split. 8 ch/lane (b128 reads):
// lane = px4(4) x g(8) x half(2); 2 wave-iters, fully unrolled.
// 64.5KB LDS, 2 blocks/CU, 512 blocks.
// ---------------------------------------------------------------------------
__global__ __launch_bounds__(512) void dcn_sample(
    const unsigned short* __restrict__ vbf,    // [n][4096][256] bf16
    const unsigned short* __restrict__ ombf,   // [m][432] bf16
    unsigned short* __restrict__ sampled)      // [m][256] bf16
{
    __shared__ unsigned short v_s[144 * 128];  // 36864 B
    __shared__ unsigned short om_s[64 * 216];  // 27648 B
    const int t = threadIdx.x;
    const int b = blockIdx.x;
    const int chalf = b & 1;
    const int tile  = b >> 1;
    const int n   = tile >> 6;
    const int py0 = ((tile >> 3) & 7) * 8;
    const int px0 = (tile & 7) * 8;
    const int y0t = py0 - 2, x0t = px0 - 2;
    const int wub = t & ~63;                   // wave-uniform thread base

    {   // stage v half-tile: 2304 uint4
        const unsigned short* vn = vbf + ((size_t)n << 12) * 256 + chalf * 128;
#pragma unroll
        for (int jj = 0; jj < 5; jj++) {
            const int j = jj * 512 + t;
            if (j < 2304) {
                const int slot = j >> 4, wi = j & 15;
                const int ly = slot / 12, lx = slot - ly * 12;
                const int gy = min(max(y0t + ly, 0), 63);
                const int gx = min(max(x0t + lx, 0), 63);
                gload16(vn + (size_t)((gy << 6) + gx) * 256 + wi * 8,
                        v_s + (size_t)(jj * 512 + wub) * 8);
            }
        }
        // stage om half: 1728 uint4
#pragma unroll
        for (int jj = 0; jj < 4; jj++) {
            const int j = jj * 512 + t;
            if (j < 1728) {
                const int pl = j / 27, wi = j - pl * 27;
                const int m = (n << 12) + ((py0 + (pl >> 3)) << 6) + px0 + (pl & 7);
                gload16(ombf + (size_t)m * OMC + chalf * 216 + wi * 8,
                        om_s + (size_t)(jj * 512 + wub) * 8);
            }
        }
    }
    __syncthreads();

    const int lane = t & 63;
    const int wv   = t >> 6;             // wave id 0..7
    const int px4  = lane >> 4;          // 0..3
    const int g    = (lane >> 1) & 7;    // local group 0..7
    const int half = lane & 1;
    const int chl  = g * 16 + half * 8;  // local channel 0..127 step 8

#pragma unroll
    for (int i = 0; i < 2; i++) {
        const int pl = wv * 8 + i * 4 + px4;
        const int h  = py0 + (pl >> 3);
        const int w  = px0 + (pl & 7);
        const unsigned short* omr = om_s + pl * 216 + g * 27;
        float acc[8];
#pragma unroll
        for (int c = 0; c < 8; c++) acc[c] = 0.f;
#pragma unroll
        for (int k = 0; k < 9; k++) {
            const float offy = bf2f(omr[2 * k]);
            const float offx = bf2f(omr[2 * k + 1]);
            const float mk   = bf2f(omr[18 + k]);
            const float sy = (float)(h + k / 3 - 1) + offy;
            const float sx = (float)(w + k % 3 - 1) + offx;
            const float y0f = floorf(sy), x0f = floorf(sx);
            const float fy = sy - y0f, fx = sx - x0f;
            const int y0 = (int)y0f, x0 = (int)x0f;
            const float ay  = ((unsigned)y0 < 64u) ? (1.f - fy) : 0.f;
            const float by  = ((unsigned)(y0 + 1) < 64u) ? fy : 0.f;
            const float axm = (((unsigned)x0 < 64u) ? (1.f - fx) : 0.f) * mk;
            const float bxm = (((unsigned)(x0 + 1) < 64u) ? fx : 0.f) * mk;
            const float w00 = ay * axm, w01 = ay * bxm;
            const float w10 = by * axm, w11 = by * bxm;
            const int ly = y0 - y0t, lx = x0 - x0t;
            if ((unsigned)ly <= 10u && (unsigned)lx <= 10u) {
                const unsigned short* p00 = v_s + ((ly * 12 + lx) * 128 + chl);
                acc8(p00,                  w00, acc);
                acc8(p00 + 128,            w01, acc);
                acc8(p00 + 12 * 128,       w10, acc);
                acc8(p00 + 12 * 128 + 128, w11, acc);
            } else {
                const int yc0 = min(max(y0, 0), 63), yc1 = min(max(y0 + 1, 0), 63);
                const int xc0 = min(max(x0, 0), 63), xc1 = min(max(x0 + 1, 0), 63);
                const unsigned short* vg =
                    vbf + ((size_t)n << 12) * 256 + chalf * 128 + chl;
                acc8(vg + (size_t)((yc0 << 6) + xc0) * 256, w00, acc);
                acc8(vg + (size_t)((yc0 << 6) + xc1) * 256, w01, acc);
                acc8(vg + (size_t)((yc1 << 6) + xc0) * 256, w10, acc);
                acc8(vg + (size_t)((yc1 << 6) + xc1) * 256, w11, acc);
            }
        }
        const int m = (n << 12) + (h << 6) + w;
        uint4 pk;
        pk.x = (unsigned)f2bf(acc[0]) | ((unsigned)f2bf(acc[1]) << 16);
        pk.y = (unsigned)f2bf(acc[2]) | ((unsigned)f2bf(acc[3]) << 16);
        pk.z = (unsigned)f2bf(acc[4]) | ((unsigned)f2bf(acc[5]) << 16);
        pk.w = (unsigned)f2bf(acc[6]) | ((unsigned)f2bf(acc[7]) << 16);
        *reinterpret_cast<uint4*>(sampled + (size_t)m * 256 + chalf * 128 + chl) = pk;
    }
}

// ---------------------------------------------------------------------------
// Output GEMM + fused per-block channel stats. 64x64 tile, 128 threads
// (2 waves, 64x32 each, acc[4][2]). Grid (4,256) = 1024 blocks = 4/CU.
// XCD-swizzled. o stored TRANSPOSED obfT[ch][m] bf16 (uint2 stores).
// psum[256 row-blocks][256 ch].
// ---------------------------------------------------------------------------
__global__ __launch_bounds__(128) void gemm_out(
    const unsigned short* __restrict__ A,
    const unsigned short* __restrict__ Bt,
    const float* __restrict__ bias,
    unsigned short* __restrict__ obfT,         // [256][16384]
    float* __restrict__ psum, float* __restrict__ psumsq)
{
    __shared__ unsigned short As[64 * 32];     // 4KB
    __shared__ unsigned short Bs[64 * 32];     // 4KB
    __shared__ float ssum[64];
    __shared__ float sqsum[64];
    const int t    = threadIdx.x;
    const int lane = t & 63;
    const int wc   = t >> 6;                   // wave col 0..1
    const int wub  = t & ~63;
    const int vid = blockIdx.x + 4 * blockIdx.y;   // 0..1023
    const int xcd = vid & 7;
    const int j8  = vid >> 3;             // 0..127
    const int by   = xcd * 32 + (j8 >> 2);     // 0..255
    const int row0 = by * 64;
    const int col0 = (j8 & 3) * 64;

    f32x4 acc[4][2];
#pragma unroll
    for (int m = 0; m < 4; m++)
#pragma unroll
        for (int n = 0; n < 2; n++) acc[m][n] = (f32x4)0.f;

    const unsigned short* gA = A  + (size_t)(row0 + (t >> 2)) * 256 + (t & 3) * 8;
    const unsigned short* gB = Bt + (size_t)(col0 + (t >> 2)) * 256 + (t & 3) * 8;

    const int aoff = (lane & 15) * 32 + (lane >> 4) * 8;
    const int boff = ((wc * 32) + (lane & 15)) * 32 + (lane >> 4) * 8;

    for (int k0 = 0; k0 < 256; k0 += 32) {
#pragma unroll
        for (int jj = 0; jj < 2; jj++) {
            gload16(gA + (size_t)jj * 32 * 256 + k0, As + (jj * 128 + wub) * 8);
            gload16(gB + (size_t)jj * 32 * 256 + k0, Bs + (jj * 128 + wub) * 8);
        }
        __syncthreads();

        short8v a_[4], b_[2];
#pragma unroll
        for (int m = 0; m < 4; m++)
            a_[m] = *(const short8v*)(As + aoff + m * 16 * 32);
#pragma unroll
        for (int n = 0; n < 2; n++)
            b_[n] = *(const short8v*)(Bs + boff + n * 16 * 32);
#pragma unroll
        for (int m = 0; m < 4; m++)
#pragma unroll
            for (int n = 0; n < 2; n++)
                acc[m][n] = __builtin_amdgcn_mfma_f32_16x16x32_bf16(
                    a_[m], b_[n], acc[m][n], 0, 0, 0);
        __syncthreads();
    }

    const int rbase = row0 + ((lane >> 4) << 2);
#pragma unroll
    for (int n = 0; n < 2; n++) {
        const int colL = wc * 32 + n * 16 + (lane & 15);   // 0..63 in block
        const int col  = col0 + colL;
        const float bb = bias[col];
        float s = 0.f, q = 0.f;
#pragma unroll
        for (int m = 0; m < 4; m++) {
            float v_[4];
#pragma unroll
            for (int r = 0; r < 4; r++) {
                v_[r] = acc[m][n][r] + bb;
                s += v_[r]; q += v_[r] * v_[r];
            }
            uint2 pk;
            pk.x = (unsigned)f2bf(v_[0]) | ((unsigned)f2bf(v_[1]) << 16);
            pk.y = (unsigned)f2bf(v_[2]) | ((unsigned)f2bf(v_[3]) << 16);
            *reinterpret_cast<uint2*>(obfT + (size_t)col * Mrows + rbase + m * 16) = pk;
        }
        s += __shfl_xor(s, 16); s += __shfl_xor(s, 32);
        q += __shfl_xor(q, 16); q += __shfl_xor(q, 32);
        if (lane < 16) {
            ssum[colL]  = s;
            sqsum[colL] = q;
        }
    }
    __syncthreads();
    if (t < 64) {
        psum[(size_t)by * 256 + col0 + t]   = ssum[t];
        psumsq[(size_t)by * 256 + col0 + t] = sqsum[t];
    }
}

// ---------------------------------------------------------------------------
// Fused stats finalize + normalize + SiLU, pure streaming (obfT is already
// channel-major). Grid (8 px-blocks, 32 ch-blocks); block = 8 ch x 2048 px.
// psum now has 256 row-blocks.
// ---------------------------------------------------------------------------
__global__ __launch_bounds__(256) void norm_silu_stream(
    const unsigned short* __restrict__ obfT,   // [256][16384]
    const float* __restrict__ psum, const float* __restrict__ psumsq,
    const float* __restrict__ gamma, const float* __restrict__ beta,
    float* __restrict__ out)
{
    __shared__ float meanv[8], rsigv[8];
    const int t  = threadIdx.x;
    const int c0 = blockIdx.y * 8;
    const int pb = blockIdx.x * 2048;          // global m base
    const int n  = pb >> 12;
    const int px0 = pb & 4095;

    // ---- stats prelude: reduce psum[256 rows][8 ch] via shfl ----
    {
        const int c = t >> 5, r = t & 31;
        const float* ps = psum   + c0 + c;
        const float* pq = psumsq + c0 + c;
        float s = 0.f, q = 0.f;
#pragma unroll
        for (int i = 0; i < 8; i++) {
            s += ps[(size_t)(r + i * 32) * 256];
            q += pq[(size_t)(r + i * 32) * 256];
        }
#pragma unroll
        for (int off = 1; off < 32; off <<= 1) {
            s += __shfl_xor(s, off);
            q += __shfl_xor(q, off);
        }
        if (r == 0) {
            const float inv = 1.f / (float)Mrows;
            const float mean = s * inv;
            meanv[c] = mean;
            rsigv[c] = rsqrtf(q * inv - mean * mean + EPSc);
        }
    }
    __syncthreads();

    const int ch = t >> 5;                 // 0..7
    const int lp = (t & 31) * 8;           // px offset within 256-px stripe
    const float gm = gamma[c0 + ch], bt = beta[c0 + ch];
    const float mn = meanv[ch], rs = rsigv[ch];
    const unsigned short* src = obfT + (size_t)(c0 + ch) * Mrows + pb + lp;
    float* dst = out + ((size_t)n * C2c + c0 + ch) * HWc + px0 + lp;

#pragma unroll
    for (int it = 0; it < 8; it++) {
        const uint4 u = *reinterpret_cast<const uint4*>(src + it * 256);
        float xv[8];
        xv[0] = __builtin_bit_cast(float, u.x << 16);
        xv[1] = __builtin_bit_cast(float, u.x & 0xffff0000u);
        xv[2] = __builtin_bit_cast(float, u.y << 16);
        xv[3] = __builtin_bit_cast(float, u.y & 0xffff0000u);
        xv[4] = __builtin_bit_cast(float, u.z << 16);
        xv[5] = __builtin_bit_cast(float, u.z & 0xffff0000u);
        xv[6] = __builtin_bit_cast(float, u.w << 16);
        xv[7] = __builtin_bit_cast(float, u.w & 0xffff0000u);
        float4 a, b2;
#pragma unroll
        for (int i = 0; i < 4; i++) {
            const float y = gm * (xv[i] - mn) * rs + bt;
            (&a.x)[i] = y / (1.f + expf(-y));
        }
#pragma unroll
        for (int i = 0; i < 4; i++) {
            const float y = gm * (xv[4 + i] - mn) * rs + bt;
            (&b2.x)[i] = y / (1.f + expf(-y));
        }
        *reinterpret_cast<float4*>(dst + it * 256)     = a;
        *reinterpret_cast<float4*>(dst + it * 256 + 4) = b2;
    }
}

// ---------------------------------------------------------------------------
extern "C" void kernel_launch(void* const* d_in, const int* in_sizes, int n_in,
                              void* d_out, int out_size, void* d_ws, size_t ws_size,
                              hipStream_t stream)
{
    const float* x     = (const float*)d_in[0];
    const float* Wv    = (const float*)d_in[1];
    const float* bv    = (const float*)d_in[2];
    const float* Wom   = (const float*)d_in[3];
    const float* bom   = (const float*)d_in[4];
    const float* Wout  = (const float*)d_in[5];
    const float* bout  = (const float*)d_in[6];
    const float* gamma = (const float*)d_in[7];
    const float* beta  = (const float*)d_in[8];
    float* out = (float*)d_out;

    unsigned short* us = (unsigned short*)d_ws;
    unsigned short* Ax    = us;                    // 4,194,304
    unsigned short* vbf   = Ax + 4194304;          // 4,194,304
    unsigned short* ombf  = vbf + 4194304;         // 7,077,888
    unsigned short* samp  = ombf + 7077888;        // 4,194,304
    unsigned short* obfT  = samp + 4194304;        // 4,194,304
    unsigned short* WallT = obfT + 4194304;        // 196,608
    unsigned short* WoutT = WallT + 196608;        // 65,536
    float* fs     = (float*)(WoutT + 65536);
    float* psum   = fs;                            // 65,536
    float* psumsq = psum + 65536;                  // 65,536
    float* ball   = psumsq + 65536;                // 768

    // fused conversions (x transpose + weights)
    prep<<<2051, 256, 0, stream>>>(x, Wv, Wom, Wout, bv, bom,
                                   Ax, WallT, WoutT, ball);
    // v + om GEMM, 64x128 tiles, 6 blocks/CU
    gemm_vom<<<dim3(6, 256), 128, 0, stream>>>(Ax, WallT, ball, vbf, ombf);
    // deformable sampling (LDS-tiled, channel-split, 8ch/lane, unrolled)
    dcn_sample<<<512, 512, 0, stream>>>(vbf, ombf, samp);
    // o = sampled @ Wout + bout -> obfT[ch][m] bf16, 64x64 tiles, 4/CU
    gemm_out<<<dim3(4, 256), 128, 0, stream>>>(samp, WoutT, bout, obfT, psum, psumsq);
    // fused stats finalize + normalize + SiLU (streaming, no transpose)
    norm_silu_stream<<<dim3(8, 32), 256, 0, stream>>>(obfT, psum, psumsq,
                                                      gamma, beta, out);
}

// Round 17
// 63.439 us; speedup vs baseline: 1.0301x; 1.0301x over previous
//
#include <hip/hip_runtime.h>
#include <hip/hip_bf16.h>
#include <math.h>

// Problem constants
constexpr int Nimg = 4;
constexpr int Cin  = 256;
constexpr int Hc   = 64;
constexpr int Wc   = 64;
constexpr int HWc  = Hc * Wc;          // 4096
constexpr int Mrows = Nimg * HWc;      // 16384
constexpr int Gg   = 16;
constexpr int K2c  = 9;
constexpr int OMC  = Gg * K2c * 3;     // 432
constexpr int C2c  = 256;
constexpr float EPSc = 1e-5f;

typedef __attribute__((ext_vector_type(8))) short short8v;   // 8 bf16 bits
typedef __attribute__((ext_vector_type(4))) float f32x4;

__device__ __forceinline__ unsigned short f2bf(float f) {
    return __builtin_bit_cast(unsigned short, __float2bfloat16(f));
}
__device__ __forceinline__ float bf2f(unsigned short u) {
    return __builtin_bit_cast(float, (unsigned)u << 16);
}

__device__ __forceinline__ void gload16(const unsigned short* g, unsigned short* l) {
    __builtin_amdgcn_global_load_lds(
        (const __attribute__((address_space(1))) void*)g,
        (__attribute__((address_space(3))) void*)l, 16, 0, 0);
}

// Accumulate 8 bf16 channels (16B at p) with weight wk into acc[8].
__device__ __forceinline__ void acc8(const unsigned short* p, float wk, float* a) {
    const uint4 u = *reinterpret_cast<const uint4*>(p);
    a[0] += wk * __builtin_bit_cast(float, u.x << 16);
    a[1] += wk * __builtin_bit_cast(float, u.x & 0xffff0000u);
    a[2] += wk * __builtin_bit_cast(float, u.y << 16);
    a[3] += wk * __builtin_bit_cast(float, u.y & 0xffff0000u);
    a[4] += wk * __builtin_bit_cast(float, u.z << 16);
    a[5] += wk * __builtin_bit_cast(float, u.z & 0xffff0000u);
    a[6] += wk * __builtin_bit_cast(float, u.w << 16);
    a[7] += wk * __builtin_bit_cast(float, u.w & 0xffff0000u);
}

// ---------------------------------------------------------------------------
// Fused prep: blocks [0,1024) transpose+convert x (float4 reads);
// blocks [1024,2051) convert weights to transposed bf16 + concat bias.
// ---------------------------------------------------------------------------
__global__ __launch_bounds__(256) void prep(
    const float* __restrict__ x,
    const float* __restrict__ Wv, const float* __restrict__ Wom,
    const float* __restrict__ Wout,
    const float* __restrict__ bv, const float* __restrict__ bom,
    unsigned short* __restrict__ A,
    unsigned short* __restrict__ WallT, unsigned short* __restrict__ WoutT,
    float* __restrict__ ball)
{
    __shared__ float tile[64][65];
    const int t   = threadIdx.x;
    const int bid = blockIdx.x;
    if (bid < 1024) {
        const int p0 = (bid & 63) * 64;
        const int c0 = ((bid >> 6) & 3) * 64;
        const int n  = bid >> 8;
        const float* xb = x + ((size_t)n * Cin + c0) * HWc + p0;
        {
            const int cl = t >> 4;
            const int p4 = (t & 15) * 4;
#pragma unroll
            for (int i = 0; i < 4; i++) {
                const int c = i * 16 + cl;
                const float4 f = *reinterpret_cast<const float4*>(
                    xb + (size_t)c * HWc + p4);
                tile[c][p4 + 0] = f.x;
                tile[c][p4 + 1] = f.y;
                tile[c][p4 + 2] = f.z;
                tile[c][p4 + 3] = f.w;
            }
        }
        __syncthreads();
        unsigned short* Ab = A + ((size_t)(n * HWc) + p0) * Cin + c0;
#pragma unroll
        for (int i = 0; i < 8; i++) {
            const int p  = i * 8 + (t >> 5);
            const int c2 = (t & 31) * 2;
            const unsigned lo = f2bf(tile[c2][p]);
            const unsigned hi = f2bf(tile[c2 + 1][p]);
            *(unsigned*)(Ab + (size_t)p * Cin + c2) = lo | (hi << 16);
        }
        return;
    }
    const int e = (bid - 1024) * 256 + t;
    if (e < 65536) {                       // Wv -> WallT rows 0..255
        const int nc = e >> 8, k = e & 255;
        WallT[e] = f2bf(Wv[(size_t)k * 256 + nc]);
    } else if (e < 196608) {               // Wom -> WallT rows 256..767 (pad)
        const int e2 = e - 65536;
        const int nc = e2 >> 8, k = e2 & 255;
        WallT[e] = f2bf(nc < 432 ? Wom[(size_t)k * 432 + nc] : 0.f);
    } else if (e < 262144) {               // Wout -> WoutT
        const int e3 = e - 196608;
        const int nc = e3 >> 8, k = e3 & 255;
        WoutT[e3] = f2bf(Wout[(size_t)k * 256 + nc]);
    } else if (e < 262912) {               // concat bias
        const int i = e - 262144;
        ball[i] = (i < 256) ? bv[i] : ((i < 688) ? bom[i - 256] : 0.f);
    }
}

// ---------------------------------------------------------------------------
// Fused v+om GEMM: 128x128 tiles, 768 blocks = 3/CU exact, XCD-swizzled.
// (Round-14 proven config: 256 threads, single-buffer 2-barrier K-loop.)
// ---------------------------------------------------------------------------
__global__ __launch_bounds__(256) void gemm_vom(
    const unsigned short* __restrict__ A,
    const unsigned short* __restrict__ Bt,
    const float* __restrict__ ball,
    unsigned short* __restrict__ vbf,
    unsigned short* __restrict__ ombf)
{
    __shared__ unsigned short As[128 * 32];
    __shared__ unsigned short Bs[128 * 32];
    const int t    = threadIdx.x;
    const int lane = t & 63;
    const int wr   = (t >> 7);
    const int wc   = (t >> 6) & 1;
    const int vid = blockIdx.x + 6 * blockIdx.y;   // 0..767
    const int xcd = vid & 7;
    const int j8  = vid >> 3;                      // 0..95
    const int row0 = (xcd * 16 + j8 / 6) * 128;
    const int col0 = (j8 % 6) * 128;

    f32x4 acc[4][4];
#pragma unroll
    for (int m = 0; m < 4; m++)
#pragma unroll
        for (int n = 0; n < 4; n++) acc[m][n] = (f32x4)0.f;

    const int r0   = t >> 2;
    const int koff = (t & 3) * 8;
    const unsigned short* gA = A  + (size_t)(row0 + r0) * 256 + koff;
    const unsigned short* gB = Bt + (size_t)(col0 + r0) * 256 + koff;
    const int wbase = (t & 192) * 8;

    const int aoff = ((wr * 64) + (lane & 15)) * 32 + (lane >> 4) * 8;
    const int boff = ((wc * 64) + (lane & 15)) * 32 + (lane >> 4) * 8;

    for (int k0 = 0; k0 < 256; k0 += 32) {
        gload16(gA + k0,            As + wbase);
        gload16(gA + k0 + 64 * 256, As + 2048 + wbase);
        gload16(gB + k0,            Bs + wbase);
        gload16(gB + k0 + 64 * 256, Bs + 2048 + wbase);
        __syncthreads();

        short8v a_[4], b_[4];
#pragma unroll
        for (int m = 0; m < 4; m++)
            a_[m] = *(const short8v*)(As + aoff + m * 16 * 32);
#pragma unroll
        for (int n = 0; n < 4; n++)
            b_[n] = *(const short8v*)(Bs + boff + n * 16 * 32);
#pragma unroll
        for (int m = 0; m < 4; m++)
#pragma unroll
            for (int n = 0; n < 4; n++)
                acc[m][n] = __builtin_amdgcn_mfma_f32_16x16x32_bf16(
                    a_[m], b_[n], acc[m][n], 0, 0, 0);
        __syncthreads();
    }

    const int rb = row0 + wr * 64 + ((lane >> 4) << 2);
#pragma unroll
    for (int n = 0; n < 4; n++) {
        const int gcol = col0 + wc * 64 + n * 16 + (lane & 15);
        const float bb = ball[gcol];
#pragma unroll
        for (int m = 0; m < 4; m++) {
#pragma unroll
            for (int r = 0; r < 4; r++) {
                const float val = acc[m][n][r] + bb;
                const int row = rb + m * 16 + r;
                if (gcol < 256) {
                    vbf[(size_t)row * 256 + gcol] = f2bf(val);
                } else {
                    const int oc = gcol - 256;
                    if (oc < 432)
                        ombf[(size_t)row * 432 + oc] = f2bf(val);
                }
            }
        }
    }
}

// ---------------------------------------------------------------------------
// Deformable sampling, LDS-tiled + channel-split. 8 ch/lane (b128 reads):
// lane = px4(4) x g(8) x half(2); 2 wave-iters, fully unrolled.
// 64.5KB LDS, 2 blocks/CU, 512 blocks.
// ---------------------------------------------------------------------------
__global__ __launch_bounds__(512) void dcn_sample(
    const unsigned short* __restrict__ vbf,    // [n][4096][256] bf16
    const unsigned short* __restrict__ ombf,   // [m][432] bf16
    unsigned short* __restrict__ sampled)      // [m][256] bf16
{
    __shared__ unsigned short v_s[144 * 128];  // 36864 B
    __shared__ unsigned short om_s[64 * 216];  // 27648 B
    const int t = threadIdx.x;
    const int b = blockIdx.x;
    const int chalf = b & 1;
    const int tile  = b >> 1;
    const int n   = tile >> 6;
    const int py0 = ((tile >> 3) & 7) * 8;
    const int px0 = (tile & 7) * 8;
    const int y0t = py0 - 2, x0t = px0 - 2;
    const int wub = t & ~63;                   // wave-uniform thread base

    {   // stage v half-tile: 2304 uint4
        const unsigned short* vn = vbf + ((size_t)n << 12) * 256 + chalf * 128;
#pragma unroll
        for (int jj = 0; jj < 5; jj++) {
            const int j = jj * 512 + t;
            if (j < 2304) {
                const int slot = j >> 4, wi = j & 15;
                const int ly = slot / 12, lx = slot - ly * 12;
                const int gy = min(max(y0t + ly, 0), 63);
                const int gx = min(max(x0t + lx, 0), 63);
                gload16(vn + (size_t)((gy << 6) + gx) * 256 + wi * 8,
                        v_s + (size_t)(jj * 512 + wub) * 8);
            }
        }
        // stage om half: 1728 uint4
#pragma unroll
        for (int jj = 0; jj < 4; jj++) {
            const int j = jj * 512 + t;
            if (j < 1728) {
                const int pl = j / 27, wi = j - pl * 27;
                const int m = (n << 12) + ((py0 + (pl >> 3)) << 6) + px0 + (pl & 7);
                gload16(ombf + (size_t)m * OMC + chalf * 216 + wi * 8,
                        om_s + (size_t)(jj * 512 + wub) * 8);
            }
        }
    }
    __syncthreads();

    const int lane = t & 63;
    const int wv   = t >> 6;             // wave id 0..7
    const int px4  = lane >> 4;          // 0..3
    const int g    = (lane >> 1) & 7;    // local group 0..7
    const int half = lane & 1;
    const int chl  = g * 16 + half * 8;  // local channel 0..127 step 8

#pragma unroll
    for (int i = 0; i < 2; i++) {
        const int pl = wv * 8 + i * 4 + px4;
        const int h  = py0 + (pl >> 3);
        const int w  = px0 + (pl & 7);
        const unsigned short* omr = om_s + pl * 216 + g * 27;
        float acc[8];
#pragma unroll
        for (int c = 0; c < 8; c++) acc[c] = 0.f;
#pragma unroll
        for (int k = 0; k < 9; k++) {
            const float offy = bf2f(omr[2 * k]);
            const float offx = bf2f(omr[2 * k + 1]);
            const float mk   = bf2f(omr[18 + k]);
            const float sy = (float)(h + k / 3 - 1) + offy;
            const float sx = (float)(w + k % 3 - 1) + offx;
            const float y0f = floorf(sy), x0f = floorf(sx);
            const float fy = sy - y0f, fx = sx - x0f;
            const int y0 = (int)y0f, x0 = (int)x0f;
            const float ay  = ((unsigned)y0 < 64u) ? (1.f - fy) : 0.f;
            const float by  = ((unsigned)(y0 + 1) < 64u) ? fy : 0.f;
            const float axm = (((unsigned)x0 < 64u) ? (1.f - fx) : 0.f) * mk;
            const float bxm = (((unsigned)(x0 + 1) < 64u) ? fx : 0.f) * mk;
            const float w00 = ay * axm, w01 = ay * bxm;
            const float w10 = by * axm, w11 = by * bxm;
            const int ly = y0 - y0t, lx = x0 - x0t;
            if ((unsigned)ly <= 10u && (unsigned)lx <= 10u) {
                const unsigned short* p00 = v_s + ((ly * 12 + lx) * 128 + chl);
                acc8(p00,                  w00, acc);
                acc8(p00 + 128,            w01, acc);
                acc8(p00 + 12 * 128,       w10, acc);
                acc8(p00 + 12 * 128 + 128, w11, acc);
            } else {
                const int yc0 = min(max(y0, 0), 63), yc1 = min(max(y0 + 1, 0), 63);
                const int xc0 = min(max(x0, 0), 63), xc1 = min(max(x0 + 1, 0), 63);
                const unsigned short* vg =
                    vbf + ((size_t)n << 12) * 256 + chalf * 128 + chl;
                acc8(vg + (size_t)((yc0 << 6) + xc0) * 256, w00, acc);
                acc8(vg + (size_t)((yc0 << 6) + xc1) * 256, w01, acc);
                acc8(vg + (size_t)((yc1 << 6) + xc0) * 256, w10, acc);
                acc8(vg + (size_t)((yc1 << 6) + xc1) * 256, w11, acc);
            }
        }
        const int m = (n << 12) + (h << 6) + w;
        uint4 pk;
        pk.x = (unsigned)f2bf(acc[0]) | ((unsigned)f2bf(acc[1]) << 16);
        pk.y = (unsigned)f2bf(acc[2]) | ((unsigned)f2bf(acc[3]) << 16);
        pk.z = (unsigned)f2bf(acc[4]) | ((unsigned)f2bf(acc[5]) << 16);
        pk.w = (unsigned)f2bf(acc[6]) | ((unsigned)f2bf(acc[7]) << 16);
        *reinterpret_cast<uint4*>(sampled + (size_t)m * 256 + chalf * 128 + chl) = pk;
    }
}

// ---------------------------------------------------------------------------
// Output GEMM + fused per-block channel stats. 128x64 tile, BK=32, 4 waves,
// grid (4,128) = 512 blocks = 2/CU. XCD-swizzled. o stored TRANSPOSED
// obfT[ch][m] bf16 (uint2 stores). (Round-14 proven config.)
// ---------------------------------------------------------------------------
__global__ __launch_bounds__(256) void gemm_out(
    const unsigned short* __restrict__ A,
    const unsigned short* __restrict__ Bt,
    const float* __restrict__ bias,
    unsigned short* __restrict__ obfT,         // [256][16384]
    float* __restrict__ psum, float* __restrict__ psumsq)
{
    __shared__ unsigned short As[128 * 32];
    __shared__ unsigned short Bs[64 * 32];
    __shared__ float ssum[2][64];
    __shared__ float sqsum[2][64];
    const int t    = threadIdx.x;
    const int lane = t & 63;
    const int wr   = (t >> 7);
    const int wc   = (t >> 6) & 1;
    const int vid = blockIdx.x + 4 * blockIdx.y;   // 0..511
    const int xcd = vid & 7;
    const int j8  = vid >> 3;             // 0..63
    const int by   = xcd * 16 + (j8 >> 2);
    const int row0 = by * 128;
    const int col0 = (j8 & 3) * 64;

    f32x4 acc[4][2];
#pragma unroll
    for (int m = 0; m < 4; m++)
#pragma unroll
        for (int n = 0; n < 2; n++) acc[m][n] = (f32x4)0.f;

    const int r0   = t >> 2;
    const int koff = (t & 3) * 8;
    const unsigned short* gA = A  + (size_t)(row0 + r0) * 256 + koff;
    const unsigned short* gB = Bt + (size_t)(col0 + (r0 & 63)) * 256 + koff;
    const int wbase = (t & 192) * 8;

    const int aoff = ((wr * 64) + (lane & 15)) * 32 + (lane >> 4) * 8;
    const int boff = ((wc * 32) + (lane & 15)) * 32 + (lane >> 4) * 8;

    for (int k0 = 0; k0 < 256; k0 += 32) {
        gload16(gA + k0,            As + wbase);
        gload16(gA + k0 + 64 * 256, As + 2048 + wbase);
        gload16(gB + k0,            Bs + wbase);
        __syncthreads();

        short8v a_[4], b_[2];
#pragma unroll
        for (int m = 0; m < 4; m++)
            a_[m] = *(const short8v*)(As + aoff + m * 16 * 32);
#pragma unroll
        for (int n = 0; n < 2; n++)
            b_[n] = *(const short8v*)(Bs + boff + n * 16 * 32);
#pragma unroll
        for (int m = 0; m < 4; m++)
#pragma unroll
            for (int n = 0; n < 2; n++)
                acc[m][n] = __builtin_amdgcn_mfma_f32_16x16x32_bf16(
                    a_[m], b_[n], acc[m][n], 0, 0, 0);
        __syncthreads();
    }

    const int rbase = row0 + wr * 64 + ((lane >> 4) << 2);
    const int cloc  = wc * 32 + (lane & 15);
#pragma unroll
    for (int n = 0; n < 2; n++) {
        const int col = col0 + cloc + n * 16;
        const float bb = bias[col];
        float s = 0.f, q = 0.f;
#pragma unroll
        for (int m = 0; m < 4; m++) {
            float v_[4];
#pragma unroll
            for (int r = 0; r < 4; r++) {
                v_[r] = acc[m][n][r] + bb;
                s += v_[r]; q += v_[r] * v_[r];
            }
            uint2 pk;
            pk.x = (unsigned)f2bf(v_[0]) | ((unsigned)f2bf(v_[1]) << 16);
            pk.y = (unsigned)f2bf(v_[2]) | ((unsigned)f2bf(v_[3]) << 16);
            *reinterpret_cast<uint2*>(obfT + (size_t)col * Mrows + rbase + m * 16) = pk;
        }
        s += __shfl_xor(s, 16); s += __shfl_xor(s, 32);
        q += __shfl_xor(q, 16); q += __shfl_xor(q, 32);
        if (lane < 16) {
            ssum[wr][cloc + n * 16]  = s;
            sqsum[wr][cloc + n * 16] = q;
        }
    }
    __syncthreads();
    if (t < 64) {
        psum[(size_t)by * 256 + col0 + t]   = ssum[0][t] + ssum[1][t];
        psumsq[(size_t)by * 256 + col0 + t] = sqsum[0][t] + sqsum[1][t];
    }
}

// ---------------------------------------------------------------------------
// Fused stats finalize + normalize + SiLU, pure streaming (obfT is already
// channel-major). Grid (16,32) = 512 blocks = 2/CU; block = 8 ch x 1024 px.
// ---------------------------------------------------------------------------
__global__ __launch_bounds__(256) void norm_silu_stream(
    const unsigned short* __restrict__ obfT,   // [256][16384]
    const float* __restrict__ psum, const float* __restrict__ psumsq,
    const float* __restrict__ gamma, const float* __restrict__ beta,
    float* __restrict__ out)
{
    __shared__ float meanv[8], rsigv[8];
    const int t  = threadIdx.x;
    const int c0 = blockIdx.y * 8;
    const int pb = blockIdx.x * 1024;          // global m base
    const int n  = pb >> 12;
    const int px0 = pb & 4095;

    // ---- stats prelude: reduce psum[128 rows][8 ch] via shfl ----
    {
        const int c = t >> 5, r = t & 31;
        const float* ps = psum   + c0 + c;
        const float* pq = psumsq + c0 + c;
        float s = 0.f, q = 0.f;
#pragma unroll
        for (int i = 0; i < 4; i++) {
            s += ps[(size_t)(r + i * 32) * 256];
            q += pq[(size_t)(r + i * 32) * 256];
        }
#pragma unroll
        for (int off = 1; off < 32; off <<= 1) {
            s += __shfl_xor(s, off);
            q += __shfl_xor(q, off);
        }
        if (r == 0) {
            const float inv = 1.f / (float)Mrows;
            const float mean = s * inv;
            meanv[c] = mean;
            rsigv[c] = rsqrtf(q * inv - mean * mean + EPSc);
        }
    }
    __syncthreads();

    const int ch = t >> 5;                 // 0..7
    const int lp = (t & 31) * 8;           // px offset within 256-px stripe
    const float gm = gamma[c0 + ch], bt = beta[c0 + ch];
    const float mn = meanv[ch], rs = rsigv[ch];
    const unsigned short* src = obfT + (size_t)(c0 + ch) * Mrows + pb + lp;
    float* dst = out + ((size_t)n * C2c + c0 + ch) * HWc + px0 + lp;

#pragma unroll
    for (int it = 0; it < 4; it++) {
        const uint4 u = *reinterpret_cast<const uint4*>(src + it * 256);
        float xv[8];
        xv[0] = __builtin_bit_cast(float, u.x << 16);
        xv[1] = __builtin_bit_cast(float, u.x & 0xffff0000u);
        xv[2] = __builtin_bit_cast(float, u.y << 16);
        xv[3] = __builtin_bit_cast(float, u.y & 0xffff0000u);
        xv[4] = __builtin_bit_cast(float, u.z << 16);
        xv[5] = __builtin_bit_cast(float, u.z & 0xffff0000u);
        xv[6] = __builtin_bit_cast(float, u.w << 16);
        xv[7] = __builtin_bit_cast(float, u.w & 0xffff0000u);
        float4 a, b2;
#pragma unroll
        for (int i = 0; i < 4; i++) {
            const float y = gm * (xv[i] - mn) * rs + bt;
            (&a.x)[i] = y / (1.f + expf(-y));
        }
#pragma unroll
        for (int i = 0; i < 4; i++) {
            const float y = gm * (xv[4 + i] - mn) * rs + bt;
            (&b2.x)[i] = y / (1.f + expf(-y));
        }
        *reinterpret_cast<float4*>(dst + it * 256)     = a;
        *reinterpret_cast<float4*>(dst + it * 256 + 4) = b2;
    }
}

// ---------------------------------------------------------------------------
extern "C" void kernel_launch(void* const* d_in, const int* in_sizes, int n_in,
                              void* d_out, int out_size, void* d_ws, size_t ws_size,
                              hipStream_t stream)
{
    const float* x     = (const float*)d_in[0];
    const float* Wv    = (const float*)d_in[1];
    const float* bv    = (const float*)d_in[2];
    const float* Wom   = (const float*)d_in[3];
    const float* bom   = (const float*)d_in[4];
    const float* Wout  = (const float*)d_in[5];
    const float* bout  = (const float*)d_in[6];
    const float* gamma = (const float*)d_in[7];
    const float* beta  = (const float*)d_in[8];
    float* out = (float*)d_out;

    unsigned short* us = (unsigned short*)d_ws;
    unsigned short* Ax    = us;                    // 4,194,304
    unsigned short* vbf   = Ax + 4194304;          // 4,194,304
    unsigned short* ombf  = vbf + 4194304;         // 7,077,888
    unsigned short* samp  = ombf + 7077888;        // 4,194,304
    unsigned short* obfT  = samp + 4194304;        // 4,194,304
    unsigned short* WallT = obfT + 4194304;        // 196,608
    unsigned short* WoutT = WallT + 196608;        // 65,536
    float* fs     = (float*)(WoutT + 65536);
    float* psum   = fs;                            // 32,768
    float* psumsq = psum + 32768;                  // 32,768
    float* ball   = psumsq + 32768;                // 768

    // fused conversions (x transpose + weights)
    prep<<<2051, 256, 0, stream>>>(x, Wv, Wom, Wout, bv, bom,
                                   Ax, WallT, WoutT, ball);
    // v (cols 0..255) + om (cols 256..687), 128x128 tiles, 3 blocks/CU exact
    gemm_vom<<<dim3(6, 128), 256, 0, stream>>>(Ax, WallT, ball, vbf, ombf);
    // deformable sampling (LDS-tiled, channel-split, 8ch/lane, unrolled)
    dcn_sample<<<512, 512, 0, stream>>>(vbf, ombf, samp);
    // o = sampled @ Wout + bout -> obfT[ch][m] bf16, 128x64 tiles, 2/CU
    gemm_out<<<dim3(4, 128), 256, 0, stream>>>(samp, WoutT, bout, obfT, psum, psumsq);
    // fused stats finalize + normalize + SiLU (streaming, 2 blocks/CU)
    norm_silu_stream<<<dim3(16, 32), 256, 0, stream>>>(obfT, psum, psumsq,
                                                       gamma, beta, out);
}